// Round 7
// baseline (74127.356 us; speedup 1.0000x reference)
//
#include <hip/hip_runtime.h>
#include <hip/hip_bf16.h>

#define TSTEPS 4096
#define XD 256
#define HD 2048
#define YD 256
#define KD 2304   // XD + HD
#define NWG 256
#define NT 512

// ---- LDS layout (bytes) ----
#define WU_OFF 0
#define WR_OFF (8*KD*2)              // 36864
#define WC_OFF (16*KD*2)             // 73728
#define WY_OFF (24*KD*2)             // 110592
#define HBUF_OFF (WY_OFF + HD*4)     // 118784  h_{t-1} (2048 f, tag-perturbed)
#define ZBUF_OFF (HBUF_OFF + HD*4)   // 126976  z = r*h  (2048 f, tag-perturbed)
#define RED_OFF (ZBUF_OFF + HD*4)    // 135168  yp[8..15], bu[16..23], br[24..31], bc[32..39], by[40], hclean[56..63]
#define LDS_BYTES (RED_OFF + 256)    // 135424

// ---- workspace ----
// Hub-republish digest relay (4 LLC legs, minimal readers):
//  producers -> private 128B line, tagged fire-and-forget (1 writer/line)
//  hub WG0   -> 1 poller per producer line, certify 8 tags, republish 32B
//               into compact 8KB digest (no barrier, per-chunk pipelining)
//  consumers -> poll OWN 16B digest chunk: detection IS the data load
// Digest lines are hub-written only; producer lines are hub-read only ->
// the produce window never sees a multi-reader storm (R1/R4 lessons).
#define HP0_OFF 0                    // h producer lines: 256 x 128B = 32KB
#define HP1_OFF 32768
#define ZP0_OFF 65536                // z producer lines
#define ZP1_OFF 98304
#define HD0_OFF 131072               // h digest: 8KB
#define HD1_OFF 139264
#define ZD0_OFF 147456               // z digest
#define ZD1_OFF 155648
#define WS_ZERO_BYTES 163840         // all lines tag 0; first epochs are 1/2
#define LSTRIDE 32                   // floats per producer line

__device__ __forceinline__ float bflo(unsigned u){ return __uint_as_float(u << 16); }
__device__ __forceinline__ float bfhi(unsigned u){ return __uint_as_float(u & 0xffff0000u); }
__device__ __forceinline__ unsigned short f2bf(float f){
  unsigned b = __float_as_uint(f);
  b += 0x7fffu + ((b >> 16) & 1u);   // RTNE (inputs finite)
  return (unsigned short)(b >> 16);
}
__device__ __forceinline__ float sigmoidf_(float x){ return 1.0f / (1.0f + __expf(-x)); }

// Tagged publish: dword store is atomic (no tearing); low-2-bit epoch tag
// self-certifies visibility at LLC. <=3 ULP perturbation (R4/R5: absmax
// unchanged at 0.001953125); recurrence uses a clean fp32 LDS carry.
__device__ __forceinline__ void storetag(float* p, float v, unsigned tag){
  unsigned b = (__float_as_uint(v) & ~3u) | tag;
  __hip_atomic_store((unsigned*)p, b, __ATOMIC_RELAXED, __HIP_MEMORY_SCOPE_AGENT);
}

// Hub republish: 8 relaxed agent-scope dword stores (fire-and-forget).
// (hipcc rejects float4 asm INPUTS — R6 lesson — so no dwordx4 store asm.
// Per-dword atomicity suffices: consumers certify all 4 tags of a chunk.)
__device__ __forceinline__ void stchunk32(float* p, float4 a, float4 b){
  unsigned* q = (unsigned*)p;
  __hip_atomic_store(q+0, __float_as_uint(a.x), __ATOMIC_RELAXED, __HIP_MEMORY_SCOPE_AGENT);
  __hip_atomic_store(q+1, __float_as_uint(a.y), __ATOMIC_RELAXED, __HIP_MEMORY_SCOPE_AGENT);
  __hip_atomic_store(q+2, __float_as_uint(a.z), __ATOMIC_RELAXED, __HIP_MEMORY_SCOPE_AGENT);
  __hip_atomic_store(q+3, __float_as_uint(a.w), __ATOMIC_RELAXED, __HIP_MEMORY_SCOPE_AGENT);
  __hip_atomic_store(q+4, __float_as_uint(b.x), __ATOMIC_RELAXED, __HIP_MEMORY_SCOPE_AGENT);
  __hip_atomic_store(q+5, __float_as_uint(b.y), __ATOMIC_RELAXED, __HIP_MEMORY_SCOPE_AGENT);
  __hip_atomic_store(q+6, __float_as_uint(b.z), __ATOMIC_RELAXED, __HIP_MEMORY_SCOPE_AGENT);
  __hip_atomic_store(q+7, __float_as_uint(b.w), __ATOMIC_RELAXED, __HIP_MEMORY_SCOPE_AGENT);
}

// Hub poll of one producer's 32B payload: certify all 8 epoch tags.
__device__ __forceinline__ void polline32(const float4* p, unsigned tag, long* budget,
                                          float4& r0, float4& r1){
  for (;;) {
    asm volatile("global_load_dwordx4 %0, %2, off sc1\n\t"
                 "global_load_dwordx4 %1, %2, off offset:16 sc1\n\t"
                 "s_waitcnt vmcnt(0)"
                 : "=v"(r0), "=v"(r1) : "v"(p) : "memory");
    unsigned m = (__float_as_uint(r0.x)^tag) | (__float_as_uint(r0.y)^tag)
               | (__float_as_uint(r0.z)^tag) | (__float_as_uint(r0.w)^tag)
               | (__float_as_uint(r1.x)^tag) | (__float_as_uint(r1.y)^tag)
               | (__float_as_uint(r1.z)^tag) | (__float_as_uint(r1.w)^tag);
    if ((m & 3u) == 0u) return;
    if (--(*budget) < 0) return;     // anti-hang
    __builtin_amdgcn_s_sleep(1);
  }
}

// Consumer poll of own 16B digest chunk: all 4 tags match -> certified data.
__device__ __forceinline__ float4 pollchunk16(const float4* p, unsigned tag, long* budget){
  for (;;) {
    float4 r;
    asm volatile("global_load_dwordx4 %0, %1, off sc1\n\t"
                 "s_waitcnt vmcnt(0)"
                 : "=v"(r) : "v"(p) : "memory");
    unsigned m = (__float_as_uint(r.x)^tag) | (__float_as_uint(r.y)^tag)
               | (__float_as_uint(r.z)^tag) | (__float_as_uint(r.w)^tag);
    if ((m & 3u) == 0u) return r;
    if (--(*budget) < 0) return r;   // anti-hang
    __builtin_amdgcn_s_sleep(1);
  }
}

// Unrolled K-chunk of a column dot.
template<int I0, int I1, int STRIDE>
__device__ __forceinline__ void dotacc(const float* v, const unsigned short* wcol,
                                       int lane, float4& acc){
  #pragma unroll
  for (int i = I0; i < I1; ++i) {
    int k = 4 * (lane + STRIDE * i);
    float4 vv = *(const float4*)(v + k);
    uint2  wq = *(const uint2*)(wcol + k);
    acc.x = fmaf(vv.x, bflo(wq.x), acc.x);
    acc.y = fmaf(vv.y, bfhi(wq.x), acc.y);
    acc.z = fmaf(vv.z, bflo(wq.y), acc.z);
    acc.w = fmaf(vv.w, bfhi(wq.y), acc.w);
  }
}
__device__ __forceinline__ void xpart(const float4 xq, const unsigned short* wcol,
                                      int l6, float4& acc){
  uint2 wq = *(const uint2*)(wcol + 4*l6);
  acc.x = fmaf(xq.x, bflo(wq.x), acc.x);
  acc.y = fmaf(xq.y, bfhi(wq.x), acc.y);
  acc.z = fmaf(xq.z, bflo(wq.y), acc.z);
  acc.w = fmaf(xq.w, bfhi(wq.y), acc.w);
}
__device__ __forceinline__ float redux64(float4 a){
  float s = (a.x + a.y) + (a.z + a.w);
  s += __shfl_xor(s, 32); s += __shfl_xor(s, 16); s += __shfl_xor(s, 8);
  s += __shfl_xor(s, 4);  s += __shfl_xor(s, 2);  s += __shfl_xor(s, 1);
  return s;
}

extern "C" __global__ void __launch_bounds__(NT)
gru_persistent(const float* __restrict__ x,  const float* __restrict__ h0,
               const float* __restrict__ Wc, const float* __restrict__ Wu,
               const float* __restrict__ Wr, const float* __restrict__ bc,
               const float* __restrict__ bu, const float* __restrict__ br,
               const float* __restrict__ Wy, const float* __restrict__ by,
               float* __restrict__ out, unsigned* wsu)
{
  extern __shared__ char smem[];
  unsigned short* wuS = (unsigned short*)(smem + WU_OFF);
  unsigned short* wrS = (unsigned short*)(smem + WR_OFF);
  unsigned short* wcS = (unsigned short*)(smem + WC_OFF);
  float* wyS   = (float*)(smem + WY_OFF);
  float* hbufS = (float*)(smem + HBUF_OFF);
  float* zbufS = (float*)(smem + ZBUF_OFF);
  float* red   = (float*)(smem + RED_OFF);

  float* hp[2]  = { (float*)((char*)wsu + HP0_OFF), (float*)((char*)wsu + HP1_OFF) };
  float* zp[2]  = { (float*)((char*)wsu + ZP0_OFF), (float*)((char*)wsu + ZP1_OFF) };
  float* hdg[2] = { (float*)((char*)wsu + HD0_OFF), (float*)((char*)wsu + HD1_OFF) };
  float* zdg[2] = { (float*)((char*)wsu + ZD0_OFF), (float*)((char*)wsu + ZD1_OFF) };

  const int wg = blockIdx.x, tid = threadIdx.x;
  const int col0 = 8 * wg;

  // ---- one-time weight staging: WG j owns gate cols [8j,8j+8), y col j ----
  for (int idx = tid; idx < 8*KD; idx += NT) {
    int c = idx & 7, k = idx >> 3;
    size_t g = (size_t)k * HD + col0 + c;   // W is [KD, 2048] row-major
    wuS[c*KD + k] = f2bf(Wu[g]);
    wrS[c*KD + k] = f2bf(Wr[g]);
    wcS[c*KD + k] = f2bf(Wc[g]);
  }
  for (int k = tid; k < HD; k += NT) wyS[k] = Wy[(size_t)k * YD + wg];
  if (tid < 8) {
    red[16+tid] = bu[col0+tid];
    red[24+tid] = br[col0+tid];
    red[32+tid] = bc[col0+tid];
    red[56+tid] = h0[col0+tid];     // clean fp32 carry of own h slice
  }
  if (tid == 0) red[40] = by[wg];
  __syncthreads();

  long budget = 20000000;

  const int w  = tid >> 6, l6 = tid & 63;          // wave / lane
  const unsigned short* ucol = wuS + w * KD;
  const unsigned short* rcol = wrS + w * KD;
  const unsigned short* ccol = wcS + w * KD;

  float4 xq = ((const float4*)x)[l6];              // per-thread x chunk
  float ureg = 0.f;

  // hidden-window work (off critical path): u gate, y[t-1] partials,
  // x_{t+1} prefetch. Runs under the z-relay latency.
  auto window = [&](int t){
    float4 au = make_float4(0.f, 0.f, 0.f, 0.f);
    xpart(xq, ucol, l6, au);
    dotacc<1, 9, 64>(hbufS - XD, ucol, l6, au);
    ureg = sigmoidf_(redux64(au) + red[16 + w]);
    int k = 256 * w + 4 * l6;
    float4 hv4 = *(const float4*)(hbufS + k);
    float4 wy4 = *(const float4*)(wyS + k);
    float ys = fmaf(hv4.x, wy4.x, fmaf(hv4.y, wy4.y, fmaf(hv4.z, wy4.z, hv4.w * wy4.w)));
    ys += __shfl_xor(ys, 32); ys += __shfl_xor(ys, 16); ys += __shfl_xor(ys, 8);
    ys += __shfl_xor(ys, 4);  ys += __shfl_xor(ys, 2);  ys += __shfl_xor(ys, 1);
    if (l6 == 0) red[8 + w] = ys;
    if (t + 1 < TSTEPS) xq = ((const float4*)(x + (size_t)(t+1) * XD))[l6];
  };

  for (int t = 0; t < TSTEPS; ++t) {
    // r x-part (registers) — ahead of the h relay
    float4 a1 = make_float4(0.f, 0.f, 0.f, 0.f);
    xpart(xq, rcol, l6, a1);

    // ---- h_{t-1} relay (consume h produced at step t-1, tag t&3) ----
    if (t == 0) {
      ((float4*)hbufS)[tid] = ((const float4*)h0)[tid];
      __syncthreads();
    } else if (wg == 0) {
      if (tid < NWG) {
        float4 r0, r1;
        polline32((const float4*)hp[(t+1)&1] + tid*(LSTRIDE/4),
                  (unsigned)(t & 3), &budget, r0, r1);
        stchunk32(hdg[(t+1)&1] + 8*tid, r0, r1);   // republish (no barrier)
        ((float4*)hbufS)[2*tid]   = r0;
        ((float4*)hbufS)[2*tid+1] = r1;
      }
      __syncthreads();                           // S1: h visible in LDS
    } else {
      float4 hv = pollchunk16((const float4*)hdg[(t+1)&1] + tid,
                              (unsigned)(t & 3), &budget);
      ((float4*)hbufS)[tid] = hv;                // detection IS the data
      __syncthreads();                           // S1
    }

    // ---- critical r-dot: wave w -> col col0+w, h part ----
    dotacc<1, 9, 64>(hbufS - XD, rcol, l6, a1);
    {
      float s = redux64(a1);
      if (l6 == 0)
        storetag(zp[t&1] + wg*LSTRIDE + w,
                 sigmoidf_(s + red[24 + w]) * red[56 + w],   // z = r*h (clean carry)
                 (unsigned)((t+1) & 3));                     // fire-and-forget
    }

    // c x-part with x_t BEFORE window's prefetch overwrites xq
    float4 a2 = make_float4(0.f, 0.f, 0.f, 0.f);
    xpart(xq, ccol, l6, a2);

    // ---- z relay ----
    if (wg == 0) {
      if (tid < NWG) {
        float4 r0, r1;
        polline32((const float4*)zp[t&1] + tid*(LSTRIDE/4),
                  (unsigned)((t+1) & 3), &budget, r0, r1);
        stchunk32(zdg[t&1] + 8*tid, r0, r1);     // republish
        ((float4*)zbufS)[2*tid]   = r0;
        ((float4*)zbufS)[2*tid+1] = r1;
      }
      window(t);                                 // hub window hides store flight
      __syncthreads();                           // S2: z + y-partials visible
    } else {
      window(t);                                 // consumers: window first
      float4 zv = pollchunk16((const float4*)zdg[t&1] + tid,
                              (unsigned)((t+1) & 3), &budget);
      ((float4*)zbufS)[tid] = zv;
      __syncthreads();                           // S2
    }

    // y[t-1] store: fire-and-forget, hidden under phase 2
    if (tid == 0 && t > 0) {
      float y = red[8]+red[9]+red[10]+red[11]+red[12]+red[13]+red[14]+red[15] + red[40];
      out[(size_t)(t-1) * YD + wg] = y;
    }

    // ---- phase 2: candidate (wave w -> col col0+w) ----
    dotacc<1, 9, 64>(zbufS - XD, ccol, l6, a2);
    {
      float s = redux64(a2);
      if (l6 == 0) {
        float cc = tanhf(s + red[32 + w]);
        float hp_ = red[56 + w];                 // clean fp32 carry
        float hn = cc * ureg + hp_ * (1.0f - ureg);
        red[56 + w] = hn;
        storetag(hp[t&1] + wg*LSTRIDE + w, hn,
                 (unsigned)((t+1) & 3));         // fire-and-forget
      }
    }
    // no trailing barrier: next relay's poll + S1 guards LDS reuse
  }

  // ---- epilogue: y[T-1] and h_fin (h of step TSTEPS-1 is in hp[(TSTEPS+1)&1]) ----
  if (wg == 0) {
    if (tid < NWG) {
      float4 r0, r1;
      polline32((const float4*)hp[(TSTEPS+1)&1] + tid*(LSTRIDE/4),
                (unsigned)(TSTEPS & 3), &budget, r0, r1);
      stchunk32(hdg[(TSTEPS+1)&1] + 8*tid, r0, r1);
      ((float4*)hbufS)[2*tid]   = r0;
      ((float4*)hbufS)[2*tid+1] = r1;
    }
    __syncthreads();
  } else {
    float4 hv = pollchunk16((const float4*)hdg[(TSTEPS+1)&1] + tid,
                            (unsigned)(TSTEPS & 3), &budget);
    ((float4*)hbufS)[tid] = hv;
    __syncthreads();
  }
  {
    int k = 256 * w + 4 * l6;
    float4 hv4 = *(const float4*)(hbufS + k);
    float4 wy4 = *(const float4*)(wyS + k);
    float ys = fmaf(hv4.x, wy4.x, fmaf(hv4.y, wy4.y, fmaf(hv4.z, wy4.z, hv4.w * wy4.w)));
    ys += __shfl_xor(ys, 32); ys += __shfl_xor(ys, 16); ys += __shfl_xor(ys, 8);
    ys += __shfl_xor(ys, 4);  ys += __shfl_xor(ys, 2);  ys += __shfl_xor(ys, 1);
    if (l6 == 0) red[8 + w] = ys;
  }
  __syncthreads();
  if (tid == 0) {
    float y = red[8]+red[9]+red[10]+red[11]+red[12]+red[13]+red[14]+red[15] + red[40];
    out[(size_t)(TSTEPS-1) * YD + wg] = y;
  }
  if (tid < 8) out[(size_t)TSTEPS * YD + col0 + tid] = red[56 + tid];  // clean h_fin
}

extern "C" void kernel_launch(void* const* d_in, const int* in_sizes, int n_in,
                              void* d_out, int out_size, void* d_ws, size_t ws_size,
                              hipStream_t stream) {
  const float* x  = (const float*)d_in[0];
  const float* h0 = (const float*)d_in[1];
  const float* Wc = (const float*)d_in[2];
  const float* Wu = (const float*)d_in[3];
  const float* Wr = (const float*)d_in[4];
  const float* bc = (const float*)d_in[5];
  const float* bu = (const float*)d_in[6];
  const float* br = (const float*)d_in[7];
  const float* Wy = (const float*)d_in[8];
  const float* by = (const float*)d_in[9];
  float* out = (float*)d_out;
  unsigned* wsu = (unsigned*)d_ws;

  // >64 KB dynamic LDS on gfx950 (160 KB/CU). Idempotent; capture-safe.
  (void)hipFuncSetAttribute((const void*)gru_persistent,
                            hipFuncAttributeMaxDynamicSharedMemorySize, LDS_BYTES);
  (void)hipMemsetAsync(d_ws, 0, WS_ZERO_BYTES, stream);   // all tags -> 0
  gru_persistent<<<dim3(NWG), dim3(NT), LDS_BYTES, stream>>>(
      x, h0, Wc, Wu, Wr, bc, bu, br, Wy, by, out, wsu);
}

// Round 9
// 24834.978 us; speedup vs baseline: 2.9848x; 2.9848x over previous
//
#include <hip/hip_runtime.h>
#include <hip/hip_bf16.h>

#define TSTEPS 4096
#define XD 256
#define HD 2048
#define YD 256
#define KD 2304   // XD + HD
#define NWG 256
#define NT 512

// ---- LDS layout (bytes) ----
#define WU_OFF 0
#define WR_OFF (8*KD*2)              // 36864
#define WC_OFF (16*KD*2)             // 73728
#define WY_OFF (24*KD*2)             // 110592
#define HBUF_OFF (WY_OFF + HD*4)     // 118784  h_{t-1} (2048 f, tag-perturbed)
#define ZBUF_OFF (HBUF_OFF + HD*4)   // 126976  z = r*h  (2048 f, tag-perturbed)
#define RED_OFF (ZBUF_OFF + HD*4)    // 135168  yp[8..15], bu[16..23], br[24..31], bc[32..39], by[40], hclean[56..63]
#define LDS_BYTES (RED_OFF + 256)    // 135424

// ---- workspace ----
// R9 = proven parts only:
//  producers: tagged fire-and-forget stores into PRIVATE double-buffered
//             128B lines (R7-correct) — no drain, no flag legs.
//  hub WG0:   512 threads poll 512 chunks (1 poller/chunk, R5/R7-correct),
//             republish certified chunks into a compact 8KB digest
//             (R7-correct codegen), __syncthreads (vmcnt drain = LLC
//             certification, R2-proven), then set 64 go lines.
//  consumers: R2's per-wave go spin -> ONE coalesced digest load (R2-proven).
// No line is ever read during its write window (R1/R4/R7 law).
#define HGO_U32 0                    // 64 go lines (128B apart) = 8KB
#define ZGO_U32 2048                 // 8KB
#define HP0_OFF 16384                // h producer lines: 256 x 128B = 32KB
#define HP1_OFF 49152
#define ZP0_OFF 81920                // z producer lines
#define ZP1_OFF 114688
#define HD0_OFF 147456               // h digest: 8KB
#define HD1_OFF 155648
#define ZD0_OFF 163840               // z digest
#define ZD1_OFF 172032
#define WS_ZERO_BYTES 180224         // everything (tags 0; first epochs 1/2)
#define LSTRIDE 32                   // floats per producer line

__device__ __forceinline__ float bflo(unsigned u){ return __uint_as_float(u << 16); }
__device__ __forceinline__ float bfhi(unsigned u){ return __uint_as_float(u & 0xffff0000u); }
__device__ __forceinline__ unsigned short f2bf(float f){
  unsigned b = __float_as_uint(f);
  b += 0x7fffu + ((b >> 16) & 1u);   // RTNE (inputs finite)
  return (unsigned short)(b >> 16);
}
__device__ __forceinline__ float sigmoidf_(float x){ return 1.0f / (1.0f + __expf(-x)); }

// Tagged publish: dword store is atomic; low-2-bit epoch tag self-certifies
// visibility at LLC. <=3 ULP (R4/R5/R7: absmax unchanged at 0.001953125);
// the recurrence uses a clean fp32 LDS carry so nothing accumulates.
__device__ __forceinline__ void storetag(float* p, float v, unsigned tag){
  unsigned b = (__float_as_uint(v) & ~3u) | tag;
  __hip_atomic_store((unsigned*)p, b, __ATOMIC_RELAXED, __HIP_MEMORY_SCOPE_AGENT);
}
__device__ __forceinline__ void flagst(unsigned* p, unsigned v){
  __hip_atomic_store(p, v, __ATOMIC_RELAXED, __HIP_MEMORY_SCOPE_AGENT);
}
// Proven serial go-poll (R2).
__device__ __forceinline__ void spinflag(const unsigned* p, unsigned epoch, long* budget){
  while (__hip_atomic_load(p, __ATOMIC_RELAXED, __HIP_MEMORY_SCOPE_AGENT) < epoch) {
    if (--(*budget) < 0) break;     // anti-hang: proceed rather than deadlock
    __builtin_amdgcn_s_sleep(1);
  }
}
// Hub poll of one 16B producer chunk at LLC (R7-proven).
__device__ __forceinline__ float4 pollchunk16(const float4* p, unsigned tag, long* budget){
  for (;;) {
    float4 r;
    asm volatile("global_load_dwordx4 %0, %1, off sc1\n\t"
                 "s_waitcnt vmcnt(0)"
                 : "=v"(r) : "v"(p) : "memory");
    unsigned m = (__float_as_uint(r.x)^tag) | (__float_as_uint(r.y)^tag)
               | (__float_as_uint(r.z)^tag) | (__float_as_uint(r.w)^tag);
    if ((m & 3u) == 0u) return r;
    if (--(*budget) < 0) return r;   // anti-hang
    __builtin_amdgcn_s_sleep(1);
  }
}
// Certified consumer load (post-go; sc1 = LLC-serviced). R2-proven.
__device__ __forceinline__ float4 cohload16(const float4* p){
  float4 r;
  asm volatile("global_load_dwordx4 %0, %1, off sc1\n\t"
               "s_waitcnt vmcnt(0)"
               : "=v"(r) : "v"(p) : "memory");
  return r;
}
// Hub digest write: 4 relaxed agent-scope dword stores (R7-proven codegen;
// hipcc rejects float4 asm inputs — R6 lesson). Values keep their tags.
__device__ __forceinline__ void stchunk16(float* p, float4 v){
  unsigned* q = (unsigned*)p;
  __hip_atomic_store(q+0, __float_as_uint(v.x), __ATOMIC_RELAXED, __HIP_MEMORY_SCOPE_AGENT);
  __hip_atomic_store(q+1, __float_as_uint(v.y), __ATOMIC_RELAXED, __HIP_MEMORY_SCOPE_AGENT);
  __hip_atomic_store(q+2, __float_as_uint(v.z), __ATOMIC_RELAXED, __HIP_MEMORY_SCOPE_AGENT);
  __hip_atomic_store(q+3, __float_as_uint(v.w), __ATOMIC_RELAXED, __HIP_MEMORY_SCOPE_AGENT);
}

// Unrolled K-chunk of a column dot.
template<int I0, int I1, int STRIDE>
__device__ __forceinline__ void dotacc(const float* v, const unsigned short* wcol,
                                       int lane, float4& acc){
  #pragma unroll
  for (int i = I0; i < I1; ++i) {
    int k = 4 * (lane + STRIDE * i);
    float4 vv = *(const float4*)(v + k);
    uint2  wq = *(const uint2*)(wcol + k);
    acc.x = fmaf(vv.x, bflo(wq.x), acc.x);
    acc.y = fmaf(vv.y, bfhi(wq.x), acc.y);
    acc.z = fmaf(vv.z, bflo(wq.y), acc.z);
    acc.w = fmaf(vv.w, bfhi(wq.y), acc.w);
  }
}
__device__ __forceinline__ void xpart(const float4 xq, const unsigned short* wcol,
                                      int l6, float4& acc){
  uint2 wq = *(const uint2*)(wcol + 4*l6);
  acc.x = fmaf(xq.x, bflo(wq.x), acc.x);
  acc.y = fmaf(xq.y, bfhi(wq.x), acc.y);
  acc.z = fmaf(xq.z, bflo(wq.y), acc.z);
  acc.w = fmaf(xq.w, bfhi(wq.y), acc.w);
}
__device__ __forceinline__ float redux64(float4 a){
  float s = (a.x + a.y) + (a.z + a.w);
  s += __shfl_xor(s, 32); s += __shfl_xor(s, 16); s += __shfl_xor(s, 8);
  s += __shfl_xor(s, 4);  s += __shfl_xor(s, 2);  s += __shfl_xor(s, 1);
  return s;
}

extern "C" __global__ void __launch_bounds__(NT)
gru_persistent(const float* __restrict__ x,  const float* __restrict__ h0,
               const float* __restrict__ Wc, const float* __restrict__ Wu,
               const float* __restrict__ Wr, const float* __restrict__ bc,
               const float* __restrict__ bu, const float* __restrict__ br,
               const float* __restrict__ Wy, const float* __restrict__ by,
               float* __restrict__ out, unsigned* wsu)
{
  extern __shared__ char smem[];
  unsigned short* wuS = (unsigned short*)(smem + WU_OFF);
  unsigned short* wrS = (unsigned short*)(smem + WR_OFF);
  unsigned short* wcS = (unsigned short*)(smem + WC_OFF);
  float* wyS   = (float*)(smem + WY_OFF);
  float* hbufS = (float*)(smem + HBUF_OFF);
  float* zbufS = (float*)(smem + ZBUF_OFF);
  float* red   = (float*)(smem + RED_OFF);

  unsigned* hgo = wsu + HGO_U32;
  unsigned* zgo = wsu + ZGO_U32;
  float* hp[2]  = { (float*)((char*)wsu + HP0_OFF), (float*)((char*)wsu + HP1_OFF) };
  float* zp[2]  = { (float*)((char*)wsu + ZP0_OFF), (float*)((char*)wsu + ZP1_OFF) };
  float* hdg[2] = { (float*)((char*)wsu + HD0_OFF), (float*)((char*)wsu + HD1_OFF) };
  float* zdg[2] = { (float*)((char*)wsu + ZD0_OFF), (float*)((char*)wsu + ZD1_OFF) };

  const int wg = blockIdx.x, tid = threadIdx.x;
  const int col0 = 8 * wg;

  // ---- one-time weight staging: WG j owns gate cols [8j,8j+8), y col j ----
  for (int idx = tid; idx < 8*KD; idx += NT) {
    int c = idx & 7, k = idx >> 3;
    size_t g = (size_t)k * HD + col0 + c;   // W is [KD, 2048] row-major
    wuS[c*KD + k] = f2bf(Wu[g]);
    wrS[c*KD + k] = f2bf(Wr[g]);
    wcS[c*KD + k] = f2bf(Wc[g]);
  }
  for (int k = tid; k < HD; k += NT) wyS[k] = Wy[(size_t)k * YD + wg];
  if (tid < 8) {
    red[16+tid] = bu[col0+tid];
    red[24+tid] = br[col0+tid];
    red[32+tid] = bc[col0+tid];
    red[56+tid] = h0[col0+tid];     // clean fp32 carry of own h slice
  }
  if (tid == 0) red[40] = by[wg];
  __syncthreads();

  long budget = 20000000;

  const int w  = tid >> 6, l6 = tid & 63;          // wave / lane
  const int goline = ((wg & 7) << 3) + w;          // per-wave go line (R2)
  const int pline = tid >> 1, pchk = tid & 1;      // hub poll map: 1 chunk/thread
  const unsigned short* ucol = wuS + w * KD;
  const unsigned short* rcol = wrS + w * KD;
  const unsigned short* ccol = wcS + w * KD;

  float4 xq = ((const float4*)x)[l6];              // per-thread x chunk
  float ureg = 0.f;

  // hidden-window work (off critical path): u gate, y[t-1] partials,
  // x_{t+1} prefetch. Runs under the z-relay latency.
  auto window = [&](int t){
    float4 au = make_float4(0.f, 0.f, 0.f, 0.f);
    xpart(xq, ucol, l6, au);
    dotacc<1, 9, 64>(hbufS - XD, ucol, l6, au);
    ureg = sigmoidf_(redux64(au) + red[16 + w]);
    int k = 256 * w + 4 * l6;
    float4 hv4 = *(const float4*)(hbufS + k);
    float4 wy4 = *(const float4*)(wyS + k);
    float ys = fmaf(hv4.x, wy4.x, fmaf(hv4.y, wy4.y, fmaf(hv4.z, wy4.z, hv4.w * wy4.w)));
    ys += __shfl_xor(ys, 32); ys += __shfl_xor(ys, 16); ys += __shfl_xor(ys, 8);
    ys += __shfl_xor(ys, 4);  ys += __shfl_xor(ys, 2);  ys += __shfl_xor(ys, 1);
    if (l6 == 0) red[8 + w] = ys;
    if (t + 1 < TSTEPS) xq = ((const float4*)(x + (size_t)(t+1) * XD))[l6];
  };

  for (int t = 0; t < TSTEPS; ++t) {
    // r x-part (registers) — ahead of the h relay
    float4 a1 = make_float4(0.f, 0.f, 0.f, 0.f);
    xpart(xq, rcol, l6, a1);

    // ---- h_{t-1} relay (epoch t, tag t&3, parity (t+1)&1) ----
    if (t == 0) {
      ((float4*)hbufS)[tid] = ((const float4*)h0)[tid];
      __syncthreads();                           // S1
    } else if (wg == 0) {
      // hub: certify producer chunks, republish digest, drain, go
      float4 hv = pollchunk16((const float4*)(hp[(t+1)&1] + pline*LSTRIDE + pchk*4),
                              (unsigned)(t & 3), &budget);
      stchunk16(hdg[(t+1)&1] + 4*tid, hv);       // pipelined per-chunk republish
      ((float4*)hbufS)[tid] = hv;
      __syncthreads();                           // S1 + digest certified at LLC
      if (tid < 64) flagst(hgo + tid*32, (unsigned)t);
    } else {
      if (l6 == 0) spinflag(hgo + goline*32, (unsigned)t, &budget);
      float4 hv = cohload16((const float4*)hdg[(t+1)&1] + tid);  // certified
      ((float4*)hbufS)[tid] = hv;
      __syncthreads();                           // S1
    }

    // ---- critical r-dot: wave w -> col col0+w, h part ----
    dotacc<1, 9, 64>(hbufS - XD, rcol, l6, a1);
    {
      float s = redux64(a1);
      if (l6 == 0)
        storetag(zp[t&1] + wg*LSTRIDE + w,
                 sigmoidf_(s + red[24 + w]) * red[56 + w],   // z = r*h (clean carry)
                 (unsigned)((t+1) & 3));                     // fire-and-forget
    }

    // c x-part with x_t BEFORE window's prefetch overwrites xq
    float4 a2 = make_float4(0.f, 0.f, 0.f, 0.f);
    xpart(xq, ccol, l6, a2);

    // ---- z relay (epoch t+1, tag (t+1)&3, parity t&1) ----
    if (wg == 0) {
      float4 zv = pollchunk16((const float4*)(zp[t&1] + pline*LSTRIDE + pchk*4),
                              (unsigned)((t+1) & 3), &budget);
      stchunk16(zdg[t&1] + 4*tid, zv);
      ((float4*)zbufS)[tid] = zv;
      __syncthreads();                           // drain digest stores
      if (tid < 64) flagst(zgo + tid*32, (unsigned)(t+1));
      window(t);                                 // hub: window after go
      __syncthreads();                           // S2: y-partials visible
    } else {
      window(t);                                 // consumers: window first
      if (l6 == 0) spinflag(zgo + goline*32, (unsigned)(t+1), &budget);
      float4 zv = cohload16((const float4*)zdg[t&1] + tid);
      ((float4*)zbufS)[tid] = zv;
      __syncthreads();                           // S2
    }

    // y[t-1] store: fire-and-forget, hidden under phase 2
    if (tid == 0 && t > 0) {
      float y = red[8]+red[9]+red[10]+red[11]+red[12]+red[13]+red[14]+red[15] + red[40];
      out[(size_t)(t-1) * YD + wg] = y;
    }

    // ---- phase 2: candidate (wave w -> col col0+w) ----
    dotacc<1, 9, 64>(zbufS - XD, ccol, l6, a2);
    {
      float s = redux64(a2);
      if (l6 == 0) {
        float cc = tanhf(s + red[32 + w]);
        float hp_ = red[56 + w];                 // clean fp32 carry
        float hn = cc * ureg + hp_ * (1.0f - ureg);
        red[56 + w] = hn;
        storetag(hp[t&1] + wg*LSTRIDE + w, hn,
                 (unsigned)((t+1) & 3));         // fire-and-forget
      }
    }
    // no trailing barrier: relays' spin/poll + S1/S2 guard LDS reuse
  }

  // ---- epilogue: y[T-1] and h_fin (epoch TSTEPS, tag 0, parity 1) ----
  if (wg == 0) {
    float4 hv = pollchunk16((const float4*)(hp[(TSTEPS+1)&1] + pline*LSTRIDE + pchk*4),
                            (unsigned)(TSTEPS & 3), &budget);
    stchunk16(hdg[(TSTEPS+1)&1] + 4*tid, hv);
    ((float4*)hbufS)[tid] = hv;
    __syncthreads();
    if (tid < 64) flagst(hgo + tid*32, (unsigned)TSTEPS);
  } else {
    if (l6 == 0) spinflag(hgo + goline*32, (unsigned)TSTEPS, &budget);
    float4 hv = cohload16((const float4*)hdg[(TSTEPS+1)&1] + tid);
    ((float4*)hbufS)[tid] = hv;
    __syncthreads();
  }
  {
    int k = 256 * w + 4 * l6;
    float4 hv4 = *(const float4*)(hbufS + k);
    float4 wy4 = *(const float4*)(wyS + k);
    float ys = fmaf(hv4.x, wy4.x, fmaf(hv4.y, wy4.y, fmaf(hv4.z, wy4.z, hv4.w * wy4.w)));
    ys += __shfl_xor(ys, 32); ys += __shfl_xor(ys, 16); ys += __shfl_xor(ys, 8);
    ys += __shfl_xor(ys, 4);  ys += __shfl_xor(ys, 2);  ys += __shfl_xor(ys, 1);
    if (l6 == 0) red[8 + w] = ys;
  }
  __syncthreads();
  if (tid == 0) {
    float y = red[8]+red[9]+red[10]+red[11]+red[12]+red[13]+red[14]+red[15] + red[40];
    out[(size_t)(TSTEPS-1) * YD + wg] = y;
  }
  if (tid < 8) out[(size_t)TSTEPS * YD + col0 + tid] = red[56 + tid];  // clean h_fin
}

extern "C" void kernel_launch(void* const* d_in, const int* in_sizes, int n_in,
                              void* d_out, int out_size, void* d_ws, size_t ws_size,
                              hipStream_t stream) {
  const float* x  = (const float*)d_in[0];
  const float* h0 = (const float*)d_in[1];
  const float* Wc = (const float*)d_in[2];
  const float* Wu = (const float*)d_in[3];
  const float* Wr = (const float*)d_in[4];
  const float* bc = (const float*)d_in[5];
  const float* bu = (const float*)d_in[6];
  const float* br = (const float*)d_in[7];
  const float* Wy = (const float*)d_in[8];
  const float* by = (const float*)d_in[9];
  float* out = (float*)d_out;
  unsigned* wsu = (unsigned*)d_ws;

  // >64 KB dynamic LDS on gfx950 (160 KB/CU). Idempotent; capture-safe.
  (void)hipFuncSetAttribute((const void*)gru_persistent,
                            hipFuncAttributeMaxDynamicSharedMemorySize, LDS_BYTES);
  (void)hipMemsetAsync(d_ws, 0, WS_ZERO_BYTES, stream);   // all tags/epochs -> 0
  gru_persistent<<<dim3(NWG), dim3(NT), LDS_BYTES, stream>>>(
      x, h0, Wc, Wu, Wr, bc, bu, br, Wy, by, out, wsu);
}